// Round 1
// 190.207 us; speedup vs baseline: 1.0468x; 1.0468x over previous
//
#include <hip/hip_runtime.h>
#include <hip/hip_bf16.h>
#include <stdint.h>

// Fastfood 2D conv, MI355X. fp32 I/O:
// input (16,256,32,32), B/G/S (1,4096), bias (512), P (4096) i32 -> out (16,512,32,32).
// Per pixel: patch j=kk*256+ch (2304, pad 4096), *B, FWHT4096, perm P, *G, FWHT4096,
// *S[0:512]+bias.
//
// R2 structure: each block = (b, oh); processes pixel PAIRS (ow=p, p+16) with both
// pixels packed bf16x2 into the 4096-word swizzled LDS exchange buffer (same
// conflict-free XOR swizzle as R1 -> LDS instr per pixel halves). Butterflies on
// float2 -> v_pk_add_f32. Epilogue: LDS redistribution so thread t holds channels
// 2t,2t+1 -> coalesced float2 stores to ws in PIXEL-MAJOR layout (no write
// amplification).
//
// R3: transpose_kernel rewritten as LDS-staged transpose. The old version did 64
// scalar stride-2KB loads per thread (lanes 8B apart -> 50% line use, latency-bound,
// ~84us by subtraction). New: per block (b,oh), 16 chunks of [32 ow][32 oc] staged in
// padded LDS [8][32][33]; reads are coalesced float4 along oc, writes are full 128B
// float4 rows along ow. Both LDS phases <=2-way bank aliasing (free). Expected ~12-18us.

__device__ __forceinline__ float bf2f(uint16_t u) {
    union { uint32_t i; float f; } c; c.i = ((uint32_t)u) << 16; return c.f;
}
__device__ __forceinline__ uint16_t f2bf(float f) {  // RNE
    uint32_t u = __float_as_uint(f);
    return (uint16_t)((u + 0x7FFFu + ((u >> 16) & 1u)) >> 16);
}
__device__ __forceinline__ int swz(int j) {
    return j ^ ((j >> 5) & 7) ^ (((j >> 8) & 1) * 24) ^ (((j >> 9) & 1) * 8);
}
__device__ __forceinline__ uint32_t pk2(float a, float b) {
    __hip_bfloat162 h = __float22bfloat162_rn(make_float2(a, b));
    union { __hip_bfloat162 h; uint32_t u; } c; c.h = h; return c.u;
}
__device__ __forceinline__ float2 unpk(uint32_t u) {
    return make_float2(__uint_as_float(u << 16), __uint_as_float(u & 0xFFFF0000u));
}
__device__ __forceinline__ void h16p(float2* x) {
    #pragma unroll
    for (int h = 1; h < 16; h <<= 1) {
        #pragma unroll
        for (int g = 0; g < 16; g += 2 * h) {
            #pragma unroll
            for (int u = g; u < g + h; ++u) {
                float2 a = x[u], b = x[u + h];
                x[u]     = make_float2(a.x + b.x, a.y + b.y);  // -> v_pk_add_f32
                x[u + h] = make_float2(a.x - b.x, a.y - b.y);
            }
        }
    }
}

__global__ __launch_bounds__(256, 2)
void fastfood_kernel(const float* __restrict__ in,
                     const float* __restrict__ Bm,
                     const float* __restrict__ Gm,
                     const float* __restrict__ Sm,
                     const float* __restrict__ bias,
                     const int* __restrict__ P,
                     float* __restrict__ ws,
                     float* __restrict__ out,   // used only when direct!=0
                     int direct)
{
    __shared__ uint16_t s_in[3 * 32 * 256];   // [ihrel][iw][ch] bf16, 48 KiB
    __shared__ uint32_t buf[4096];            // swizzled bf16x2 exchange, 16 KiB

    const int t  = threadIdx.x;
    const int t1 = t >> 4, t0 = t & 15;
    const int b  = blockIdx.x >> 5;
    const int oh = blockIdx.x & 31;

    // ---- stage input rows oh-1..oh+1 into LDS (coalesced float4)
    #pragma unroll
    for (int i = 0; i < 24; ++i) {
        const int idx   = t + i * 256;
        const int part  = idx & 7;
        const int ch    = (idx >> 3) & 255;
        const int ihrel = idx >> 11;
        const int ih    = oh - 1 + ihrel;
        float4 ld = make_float4(0.f, 0.f, 0.f, 0.f);
        if ((unsigned)ih < 32u) {
            ld = *reinterpret_cast<const float4*>(
                in + ((((size_t)b * 256 + ch) * 32 + ih) * 32 + part * 4));
        }
        const int base = ((ihrel * 32 + part * 4) << 8) | ch;
        s_in[base      ] = f2bf(ld.x);
        s_in[base + 256] = f2bf(ld.y);
        s_in[base + 512] = f2bf(ld.z);
        s_in[base + 768] = f2bf(ld.w);
    }

    // ---- constants
    float Bv[9];
    #pragma unroll
    for (int r = 0; r < 9; ++r) Bv[r] = Bm[r * 256 + t];
    float Gv[16]; int PAv[16];
    #pragma unroll
    for (int r = 0; r < 16; ++r) {
        Gv[r]  = Gm[r * 256 + t];
        PAv[r] = swz(P[r * 256 + t]);
    }
    const float S0 = Sm[2 * t], S1 = Sm[2 * t + 1];
    const float C0 = bias[2 * t], C1 = bias[2 * t + 1];
    __syncthreads();

    for (int p = 0; p < 16; ++p) {            // pixel pair (ow=p, ow=p+16)
        float2 x[16];
        #pragma unroll
        for (int r = 0; r < 9; ++r) {
            const int kh = r / 3, kw = r % 3;
            const int iw = p - 1 + kw, jw = iw + 16;
            float v0 = 0.f, v1 = 0.f;
            if ((unsigned)iw < 32u) v0 = bf2f(s_in[((kh * 32 + iw) << 8) | t]);
            if ((unsigned)jw < 32u) v1 = bf2f(s_in[((kh * 32 + jw) << 8) | t]);
            x[r] = make_float2(v0 * Bv[r], v1 * Bv[r]);
        }
        #pragma unroll
        for (int r = 9; r < 16; ++r) x[r] = make_float2(0.f, 0.f);

        #pragma unroll
        for (int pass = 0; pass < 2; ++pass) {
            h16p(x);                          // round A
            __syncthreads();
            #pragma unroll
            for (int r = 0; r < 16; ++r) buf[swz(256 * r + t)] = pk2(x[r].x, x[r].y);
            __syncthreads();
            #pragma unroll
            for (int r = 0; r < 16; ++r) x[r] = unpk(buf[swz(256 * t1 + 16 * r + t0)]);
            h16p(x);                          // round B
            __syncthreads();
            #pragma unroll
            for (int r = 0; r < 16; ++r) buf[swz(256 * t1 + 16 * r + t0)] = pk2(x[r].x, x[r].y);
            __syncthreads();
            #pragma unroll
            for (int r = 0; r < 16; ++r) x[r] = unpk(buf[swz(256 * t1 + 16 * t0 + r)]);
            h16p(x);                          // round C
            if (pass == 0) {                  // permutation + G (gather -> A-layout)
                __syncthreads();
                #pragma unroll
                for (int r = 0; r < 16; ++r) buf[swz(256 * t1 + 16 * t0 + r)] = pk2(x[r].x, x[r].y);
                __syncthreads();
                #pragma unroll
                for (int r = 0; r < 16; ++r) {
                    float2 v = unpk(buf[PAv[r]]);
                    x[r] = make_float2(Gv[r] * v.x, Gv[r] * v.y);
                }
            }
        }

        // ---- redistribute outputs: j = 16t + r lives in t<32; give thread t oc=2t,2t+1
        __syncthreads();
        float* bufF = reinterpret_cast<float*>(buf);  // fp32 staging (1024 floats)
        if (t < 32) {
            #pragma unroll
            for (int r = 0; r < 16; ++r) {
                const int a = 16 * t + (r ^ (t & 15));  // 2-way max bank aliasing
                bufF[a]       = x[r].x;
                bufF[a + 512] = x[r].y;
            }
        }
        __syncthreads();
        const int a0 = (2 * t) ^ ((t >> 3) & 15), a1 = a0 ^ 1;
        const float o00 = S0 * bufF[a0]       + C0;   // oc=2t,   ow=p
        const float o01 = S1 * bufF[a1]       + C1;   // oc=2t+1, ow=p
        const float o10 = S0 * bufF[a0 + 512] + C0;   // oc=2t,   ow=p+16
        const float o11 = S1 * bufF[a1 + 512] + C1;   // oc=2t+1, ow=p+16

        if (!direct) {
            const int pix0 = ((b * 32 + oh) * 32 + p);
            *reinterpret_cast<float2*>(ws + (size_t)pix0 * 512 + 2 * t)
                = make_float2(o00, o01);
            *reinterpret_cast<float2*>(ws + (size_t)(pix0 + 16) * 512 + 2 * t)
                = make_float2(o10, o11);
        } else {
            const size_t r0 = ((size_t)b * 512 + 2 * t) * 1024 + oh * 32;
            out[r0 + p]            = o00;
            out[r0 + 1024 + p]     = o01;
            out[r0 + p + 16]       = o10;
            out[r0 + 1024 + p + 16] = o11;
        }
    }
}

// ws (b,oh,ow,oc) -> out (b,oc,oh,ow).
// R3: LDS-staged transpose. Block = (b,oh). 16 chunks of [32 ow][32 oc], 8 chunks per
// LDS fill ([8][32][33] padded floats, 33.8 KiB). Read phase: float4 along oc, lanes
// contiguous -> 128B coalesced segments. Write phase: float4 along ow -> each oc row's
// full 128B line written by 8 lanes. Both LDS phases <=2-way bank aliasing.
__global__ __launch_bounds__(256)
void transpose_kernel(const float* __restrict__ ws, float* __restrict__ out)
{
    __shared__ float tile[8][32][33];

    const int t  = threadIdx.x;
    const int b  = blockIdx.x >> 5;
    const int oh = blockIdx.x & 31;
    const float* src = ws + (size_t)((b * 32 + oh) * 32) * 512;  // [ow][oc]

    const int ow_r = t >> 3;   // 0..31  read phase: ow row
    const int oq   = t & 7;    // 0..7   read phase: float4 group within 32 oc
    const int oc_w = t >> 3;   // 0..31  write phase: oc within chunk
    const int wq   = t & 7;    // 0..7   write phase: float4 group within 32 ow

    #pragma unroll
    for (int outer = 0; outer < 2; ++outer) {
        #pragma unroll
        for (int cc = 0; cc < 8; ++cc) {
            const int oc0 = (outer * 8 + cc) * 32;
            const float4 v = *reinterpret_cast<const float4*>(
                src + (size_t)ow_r * 512 + oc0 + 4 * oq);
            tile[cc][ow_r][4 * oq + 0] = v.x;
            tile[cc][ow_r][4 * oq + 1] = v.y;
            tile[cc][ow_r][4 * oq + 2] = v.z;
            tile[cc][ow_r][4 * oq + 3] = v.w;
        }
        __syncthreads();
        #pragma unroll
        for (int cc = 0; cc < 8; ++cc) {
            const int oc = (outer * 8 + cc) * 32 + oc_w;
            float4 v;
            v.x = tile[cc][4 * wq + 0][oc_w];
            v.y = tile[cc][4 * wq + 1][oc_w];
            v.z = tile[cc][4 * wq + 2][oc_w];
            v.w = tile[cc][4 * wq + 3][oc_w];
            *reinterpret_cast<float4*>(
                out + ((size_t)b * 512 + oc) * 1024 + oh * 32 + 4 * wq) = v;
        }
        __syncthreads();
    }
}

extern "C" void kernel_launch(void* const* d_in, const int* in_sizes, int n_in,
                              void* d_out, int out_size, void* d_ws, size_t ws_size,
                              hipStream_t stream) {
    const float* in   = (const float*)d_in[0];
    const float* Bm   = (const float*)d_in[1];
    const float* Gm   = (const float*)d_in[2];
    const float* Sm   = (const float*)d_in[3];
    const float* bias = (const float*)d_in[4];
    const int*   P    = (const int*)d_in[5];
    float* out = (float*)d_out;
    float* ws  = (float*)d_ws;

    const size_t need = (size_t)16 * 32 * 32 * 512 * 4;  // 33.5 MB pixel-major staging
    const int direct = (ws_size < need) ? 1 : 0;

    dim3 grid(16 * 32), block(256);
    fastfood_kernel<<<grid, block, 0, stream>>>(in, Bm, Gm, Sm, bias, P, ws, out, direct);
    if (!direct)
        transpose_kernel<<<grid, block, 0, stream>>>(ws, out);
}

// Round 2
// 170.479 us; speedup vs baseline: 1.1679x; 1.1157x over previous
//
#include <hip/hip_runtime.h>
#include <hip/hip_bf16.h>
#include <stdint.h>

// Fastfood 2D conv, MI355X. fp32 I/O:
// input (16,256,32,32), B/G/S (1,4096), bias (512), P (4096) i32 -> out (16,512,32,32).
// Per pixel: patch j=kk*256+ch (2304, pad 4096), *B, FWHT4096, perm P, *G, FWHT4096,
// *S[0:512]+bias.
//
// R4 structure: each block = (b, oh); processes pixel QUADS (ow = p, p+8, p+16, p+24,
// p=0..7). Each LDS exchange slot holds all 4 pixels: uint2 = {bf16x2(pix0,pix2),
// bf16x2(pix1,pix3)}, moved with ds_write_b64/ds_read_b64 at the SAME swizzled
// addresses as the R2 pair version -> LDS exchange instructions AND barriers per
// pixel halve vs R2/R3. Butterflies stay v_pk_add_f32 on two float2[16] arrays.
// LDS: 48 KiB s_in + 32 KiB buf = 80 KiB -> 2 blocks/CU (unchanged).
//
// R3: transpose_kernel = LDS-staged transpose (kept unchanged; ~11 us, HBM-bound).

__device__ __forceinline__ float bf2f(uint16_t u) {
    union { uint32_t i; float f; } c; c.i = ((uint32_t)u) << 16; return c.f;
}
__device__ __forceinline__ uint16_t f2bf(float f) {  // RNE
    uint32_t u = __float_as_uint(f);
    return (uint16_t)((u + 0x7FFFu + ((u >> 16) & 1u)) >> 16);
}
__device__ __forceinline__ int swz(int j) {
    return j ^ ((j >> 5) & 7) ^ (((j >> 8) & 1) * 24) ^ (((j >> 9) & 1) * 8);
}
__device__ __forceinline__ uint32_t pk2(float a, float b) {
    __hip_bfloat162 h = __float22bfloat162_rn(make_float2(a, b));
    union { __hip_bfloat162 h; uint32_t u; } c; c.h = h; return c.u;
}
__device__ __forceinline__ float2 unpk(uint32_t u) {
    return make_float2(__uint_as_float(u << 16), __uint_as_float(u & 0xFFFF0000u));
}
__device__ __forceinline__ void h16p(float2* x) {
    #pragma unroll
    for (int h = 1; h < 16; h <<= 1) {
        #pragma unroll
        for (int g = 0; g < 16; g += 2 * h) {
            #pragma unroll
            for (int u = g; u < g + h; ++u) {
                float2 a = x[u], b = x[u + h];
                x[u]     = make_float2(a.x + b.x, a.y + b.y);  // -> v_pk_add_f32
                x[u + h] = make_float2(a.x - b.x, a.y - b.y);
            }
        }
    }
}

__global__ __launch_bounds__(256, 2)
void fastfood_kernel(const float* __restrict__ in,
                     const float* __restrict__ Bm,
                     const float* __restrict__ Gm,
                     const float* __restrict__ Sm,
                     const float* __restrict__ bias,
                     const int* __restrict__ P,
                     float* __restrict__ ws,
                     float* __restrict__ out,   // used only when direct!=0
                     int direct)
{
    __shared__ uint16_t s_in[3 * 32 * 256];   // [ihrel][iw][ch] bf16, 48 KiB
    __shared__ uint2    buf2[4096];           // swizzled 4-pixel bf16 exchange, 32 KiB

    const int t  = threadIdx.x;
    const int t1 = t >> 4, t0 = t & 15;
    const int b  = blockIdx.x >> 5;
    const int oh = blockIdx.x & 31;

    // ---- stage input rows oh-1..oh+1 into LDS (coalesced float4)
    #pragma unroll
    for (int i = 0; i < 24; ++i) {
        const int idx   = t + i * 256;
        const int part  = idx & 7;
        const int ch    = (idx >> 3) & 255;
        const int ihrel = idx >> 11;
        const int ih    = oh - 1 + ihrel;
        float4 ld = make_float4(0.f, 0.f, 0.f, 0.f);
        if ((unsigned)ih < 32u) {
            ld = *reinterpret_cast<const float4*>(
                in + ((((size_t)b * 256 + ch) * 32 + ih) * 32 + part * 4));
        }
        const int base = ((ihrel * 32 + part * 4) << 8) | ch;
        s_in[base      ] = f2bf(ld.x);
        s_in[base + 256] = f2bf(ld.y);
        s_in[base + 512] = f2bf(ld.z);
        s_in[base + 768] = f2bf(ld.w);
    }

    // ---- constants
    float Bv[9];
    #pragma unroll
    for (int r = 0; r < 9; ++r) Bv[r] = Bm[r * 256 + t];
    float Gv[16]; int PAv[16];
    #pragma unroll
    for (int r = 0; r < 16; ++r) {
        Gv[r]  = Gm[r * 256 + t];
        PAv[r] = swz(P[r * 256 + t]);
    }
    const float S0 = Sm[2 * t], S1 = Sm[2 * t + 1];
    const float C0 = bias[2 * t], C1 = bias[2 * t + 1];
    __syncthreads();

    for (int p = 0; p < 8; ++p) {             // pixel quad (ow = p, p+8, p+16, p+24)
        float2 x0[16], x1[16];                // x0=(p, p+16), x1=(p+8, p+24)
        #pragma unroll
        for (int r = 0; r < 9; ++r) {
            const int kh = r / 3, kw = r % 3;
            const int iw = p - 1 + kw;        // iw in [-1, 9]
            float v0 = 0.f, v3 = 0.f;
            if ((unsigned)iw < 32u)        v0 = bf2f(s_in[((kh * 32 + iw     ) << 8) | t]);
            const float v1                    = bf2f(s_in[((kh * 32 + iw +  8) << 8) | t]);
            const float v2                    = bf2f(s_in[((kh * 32 + iw + 16) << 8) | t]);
            if ((unsigned)(iw + 24) < 32u) v3 = bf2f(s_in[((kh * 32 + iw + 24) << 8) | t]);
            x0[r] = make_float2(v0 * Bv[r], v2 * Bv[r]);
            x1[r] = make_float2(v1 * Bv[r], v3 * Bv[r]);
        }
        #pragma unroll
        for (int r = 9; r < 16; ++r) {
            x0[r] = make_float2(0.f, 0.f);
            x1[r] = make_float2(0.f, 0.f);
        }

        #pragma unroll
        for (int pass = 0; pass < 2; ++pass) {
            h16p(x0); h16p(x1);               // round A (stride 256)
            __syncthreads();
            #pragma unroll
            for (int r = 0; r < 16; ++r)
                buf2[swz(256 * r + t)] =
                    make_uint2(pk2(x0[r].x, x0[r].y), pk2(x1[r].x, x1[r].y));
            __syncthreads();
            #pragma unroll
            for (int r = 0; r < 16; ++r) {
                const uint2 u = buf2[swz(256 * t1 + 16 * r + t0)];
                x0[r] = unpk(u.x); x1[r] = unpk(u.y);
            }
            h16p(x0); h16p(x1);               // round B (stride 16)
            __syncthreads();
            #pragma unroll
            for (int r = 0; r < 16; ++r)
                buf2[swz(256 * t1 + 16 * r + t0)] =
                    make_uint2(pk2(x0[r].x, x0[r].y), pk2(x1[r].x, x1[r].y));
            __syncthreads();
            #pragma unroll
            for (int r = 0; r < 16; ++r) {
                const uint2 u = buf2[swz(256 * t1 + 16 * t0 + r)];
                x0[r] = unpk(u.x); x1[r] = unpk(u.y);
            }
            h16p(x0); h16p(x1);               // round C (stride 1)
            if (pass == 0) {                  // permutation + G (gather -> A-layout)
                __syncthreads();
                #pragma unroll
                for (int r = 0; r < 16; ++r)
                    buf2[swz(256 * t1 + 16 * t0 + r)] =
                        make_uint2(pk2(x0[r].x, x0[r].y), pk2(x1[r].x, x1[r].y));
                __syncthreads();
                #pragma unroll
                for (int r = 0; r < 16; ++r) {
                    const uint2 u = buf2[PAv[r]];
                    const float2 v0 = unpk(u.x), v1 = unpk(u.y);
                    x0[r] = make_float2(Gv[r] * v0.x, Gv[r] * v0.y);
                    x1[r] = make_float2(Gv[r] * v1.x, Gv[r] * v1.y);
                }
            }
        }

        // ---- redistribute outputs: j = 16t + r lives in t<32; give thread t oc=2t,2t+1
        __syncthreads();
        float* bufF = reinterpret_cast<float*>(buf2);  // fp32 staging (2048 floats)
        if (t < 32) {
            #pragma unroll
            for (int r = 0; r < 16; ++r) {
                const int a = 16 * t + (r ^ (t & 15));  // 2-way max bank aliasing
                bufF[a       ] = x0[r].x;   // ow = p
                bufF[a +  512] = x1[r].x;   // ow = p+8
                bufF[a + 1024] = x0[r].y;   // ow = p+16
                bufF[a + 1536] = x1[r].y;   // ow = p+24
            }
        }
        __syncthreads();
        const int a0 = (2 * t) ^ ((t >> 3) & 15), a1 = a0 ^ 1;
        #pragma unroll
        for (int k = 0; k < 4; ++k) {
            const float oA = S0 * bufF[a0 + 512 * k] + C0;   // oc=2t,   ow=p+8k
            const float oB = S1 * bufF[a1 + 512 * k] + C1;   // oc=2t+1, ow=p+8k
            if (!direct) {
                const int pix = ((b * 32 + oh) * 32 + p + 8 * k);
                *reinterpret_cast<float2*>(ws + (size_t)pix * 512 + 2 * t)
                    = make_float2(oA, oB);
            } else {
                const size_t r0 = ((size_t)b * 512 + 2 * t) * 1024 + oh * 32 + p + 8 * k;
                out[r0]        = oA;
                out[r0 + 1024] = oB;
            }
        }
    }
}

// ws (b,oh,ow,oc) -> out (b,oc,oh,ow).
// R3: LDS-staged transpose. Block = (b,oh). 16 chunks of [32 ow][32 oc], 8 chunks per
// LDS fill ([8][32][33] padded floats, 33.8 KiB). Read phase: float4 along oc, lanes
// contiguous -> 128B coalesced segments. Write phase: float4 along ow -> each oc row's
// full 128B line written by 8 lanes. Both LDS phases <=2-way bank aliasing.
__global__ __launch_bounds__(256)
void transpose_kernel(const float* __restrict__ ws, float* __restrict__ out)
{
    __shared__ float tile[8][32][33];

    const int t  = threadIdx.x;
    const int b  = blockIdx.x >> 5;
    const int oh = blockIdx.x & 31;
    const float* src = ws + (size_t)((b * 32 + oh) * 32) * 512;  // [ow][oc]

    const int ow_r = t >> 3;   // 0..31  read phase: ow row
    const int oq   = t & 7;    // 0..7   read phase: float4 group within 32 oc
    const int oc_w = t >> 3;   // 0..31  write phase: oc within chunk
    const int wq   = t & 7;    // 0..7   write phase: float4 group within 32 ow

    #pragma unroll
    for (int outer = 0; outer < 2; ++outer) {
        #pragma unroll
        for (int cc = 0; cc < 8; ++cc) {
            const int oc0 = (outer * 8 + cc) * 32;
            const float4 v = *reinterpret_cast<const float4*>(
                src + (size_t)ow_r * 512 + oc0 + 4 * oq);
            tile[cc][ow_r][4 * oq + 0] = v.x;
            tile[cc][ow_r][4 * oq + 1] = v.y;
            tile[cc][ow_r][4 * oq + 2] = v.z;
            tile[cc][ow_r][4 * oq + 3] = v.w;
        }
        __syncthreads();
        #pragma unroll
        for (int cc = 0; cc < 8; ++cc) {
            const int oc = (outer * 8 + cc) * 32 + oc_w;
            float4 v;
            v.x = tile[cc][4 * wq + 0][oc_w];
            v.y = tile[cc][4 * wq + 1][oc_w];
            v.z = tile[cc][4 * wq + 2][oc_w];
            v.w = tile[cc][4 * wq + 3][oc_w];
            *reinterpret_cast<float4*>(
                out + ((size_t)b * 512 + oc) * 1024 + oh * 32 + 4 * wq) = v;
        }
        __syncthreads();
    }
}

extern "C" void kernel_launch(void* const* d_in, const int* in_sizes, int n_in,
                              void* d_out, int out_size, void* d_ws, size_t ws_size,
                              hipStream_t stream) {
    const float* in   = (const float*)d_in[0];
    const float* Bm   = (const float*)d_in[1];
    const float* Gm   = (const float*)d_in[2];
    const float* Sm   = (const float*)d_in[3];
    const float* bias = (const float*)d_in[4];
    const int*   P    = (const int*)d_in[5];
    float* out = (float*)d_out;
    float* ws  = (float*)d_ws;

    const size_t need = (size_t)16 * 32 * 32 * 512 * 4;  // 33.5 MB pixel-major staging
    const int direct = (ws_size < need) ? 1 : 0;

    dim3 grid(16 * 32), block(256);
    fastfood_kernel<<<grid, block, 0, stream>>>(in, Bm, Gm, Sm, bias, P, ws, out, direct);
    if (!direct)
        transpose_kernel<<<grid, block, 0, stream>>>(ws, out);
}

// Round 3
// 147.523 us; speedup vs baseline: 1.3496x; 1.1556x over previous
//
#include <hip/hip_runtime.h>
#include <hip/hip_bf16.h>
#include <stdint.h>

// Fastfood 2D conv, MI355X. fp32 I/O:
// input (16,256,32,32), B/G/S (1,4096), bias (512), P (4096) i32 -> out (16,512,32,32).
// Per pixel: patch j=kk*256+ch (2304, pad 4096), *B, FWHT4096, perm P, *G, FWHT4096,
// *S[0:512]+bias.
//
// R4 structure: each block = (b, oh); processes pixel QUADS (ow = p, p+8, p+16, p+24,
// p=0..7). Each LDS exchange slot holds all 4 pixels in a uint2, moved with
// ds_write_b64/ds_read_b64 at swizzled (conflict-free) addresses.
//
// R5: fp16 is the NATIVE format of the whole FWHT pipeline. Values live as packed
// _Float16x2 (h2) registers; butterflies are v_pk_add_f16 (same 2-pixel/op rate as
// v_pk_add_f32), and the LDS exchange is a pure bitcast -> the ~1000 bf16
// pack/unpack VALU ops per quad of R4 are GONE. Permutation G-multiply is packed
// v_pk_mul_f16. Precision: fp16 rounds every butterfly stage (24 stages, 11-bit
// mantissa, ~0.24% rel) vs R4's bf16 rounding at 5 exchange points (8-bit mantissa,
// ~0.87% rel) -> absmax should IMPROVE. Range peaks O(100) << 65504.
// LDS: 48 KiB s_in + 32 KiB buf = 80 KiB -> 2 blocks/CU (unchanged).
//
// R3: transpose_kernel = LDS-staged transpose (kept unchanged; ~11 us, HBM-bound).

typedef _Float16 h2 __attribute__((ext_vector_type(2)));

__device__ __forceinline__ float bf2f(uint16_t u) {
    union { uint32_t i; float f; } c; c.i = ((uint32_t)u) << 16; return c.f;
}
__device__ __forceinline__ uint16_t f2bf(float f) {  // RNE
    uint32_t u = __float_as_uint(f);
    return (uint16_t)((u + 0x7FFFu + ((u >> 16) & 1u)) >> 16);
}
__device__ __forceinline__ int swz(int j) {
    return j ^ ((j >> 5) & 7) ^ (((j >> 8) & 1) * 24) ^ (((j >> 9) & 1) * 8);
}
__device__ __forceinline__ uint32_t h2u(h2 v) {
    union { h2 h; uint32_t u; } c; c.h = v; return c.u;
}
__device__ __forceinline__ h2 u2h(uint32_t x) {
    union { h2 h; uint32_t u; } c; c.u = x; return c.h;
}
__device__ __forceinline__ h2 pkh(float a, float b) {
    h2 r; r.x = (_Float16)a; r.y = (_Float16)b; return r;
}
__device__ __forceinline__ void h16h(h2* x) {
    #pragma unroll
    for (int h = 1; h < 16; h <<= 1) {
        #pragma unroll
        for (int g = 0; g < 16; g += 2 * h) {
            #pragma unroll
            for (int u = g; u < g + h; ++u) {
                h2 a = x[u], b = x[u + h];
                x[u]     = a + b;   // -> v_pk_add_f16
                x[u + h] = a - b;
            }
        }
    }
}

__global__ __launch_bounds__(256, 2)
void fastfood_kernel(const float* __restrict__ in,
                     const float* __restrict__ Bm,
                     const float* __restrict__ Gm,
                     const float* __restrict__ Sm,
                     const float* __restrict__ bias,
                     const int* __restrict__ P,
                     float* __restrict__ ws,
                     float* __restrict__ out,   // used only when direct!=0
                     int direct)
{
    __shared__ uint16_t s_in[3 * 32 * 256];   // [ihrel][iw][ch] bf16, 48 KiB
    __shared__ uint2    buf2[4096];           // swizzled 4-pixel fp16 exchange, 32 KiB

    const int t  = threadIdx.x;
    const int t1 = t >> 4, t0 = t & 15;
    const int b  = blockIdx.x >> 5;
    const int oh = blockIdx.x & 31;

    // ---- stage input rows oh-1..oh+1 into LDS (coalesced float4)
    #pragma unroll
    for (int i = 0; i < 24; ++i) {
        const int idx   = t + i * 256;
        const int part  = idx & 7;
        const int ch    = (idx >> 3) & 255;
        const int ihrel = idx >> 11;
        const int ih    = oh - 1 + ihrel;
        float4 ld = make_float4(0.f, 0.f, 0.f, 0.f);
        if ((unsigned)ih < 32u) {
            ld = *reinterpret_cast<const float4*>(
                in + ((((size_t)b * 256 + ch) * 32 + ih) * 32 + part * 4));
        }
        const int base = ((ihrel * 32 + part * 4) << 8) | ch;
        s_in[base      ] = f2bf(ld.x);
        s_in[base + 256] = f2bf(ld.y);
        s_in[base + 512] = f2bf(ld.z);
        s_in[base + 768] = f2bf(ld.w);
    }

    // ---- constants
    float Bv[9];
    #pragma unroll
    for (int r = 0; r < 9; ++r) Bv[r] = Bm[r * 256 + t];
    h2 Gh[16]; int PAv[16];
    #pragma unroll
    for (int r = 0; r < 16; ++r) {
        const float g = Gm[r * 256 + t];
        Gh[r]  = pkh(g, g);
        PAv[r] = swz(P[r * 256 + t]);
    }
    const float S0 = Sm[2 * t], S1 = Sm[2 * t + 1];
    const float C0 = bias[2 * t], C1 = bias[2 * t + 1];
    __syncthreads();

    for (int p = 0; p < 8; ++p) {             // pixel quad (ow = p, p+8, p+16, p+24)
        h2 x0[16], x1[16];                    // x0=(p, p+16), x1=(p+8, p+24)
        #pragma unroll
        for (int r = 0; r < 9; ++r) {
            const int kh = r / 3, kw = r % 3;
            const int iw = p - 1 + kw;        // iw in [-1, 9]
            float v0 = 0.f, v3 = 0.f;
            if ((unsigned)iw < 32u)        v0 = bf2f(s_in[((kh * 32 + iw     ) << 8) | t]);
            const float v1                    = bf2f(s_in[((kh * 32 + iw +  8) << 8) | t]);
            const float v2                    = bf2f(s_in[((kh * 32 + iw + 16) << 8) | t]);
            if ((unsigned)(iw + 24) < 32u) v3 = bf2f(s_in[((kh * 32 + iw + 24) << 8) | t]);
            x0[r] = pkh(v0 * Bv[r], v2 * Bv[r]);
            x1[r] = pkh(v1 * Bv[r], v3 * Bv[r]);
        }
        #pragma unroll
        for (int r = 9; r < 16; ++r) {
            x0[r] = pkh(0.f, 0.f);
            x1[r] = pkh(0.f, 0.f);
        }

        #pragma unroll
        for (int pass = 0; pass < 2; ++pass) {
            h16h(x0); h16h(x1);               // round A (stride 256)
            __syncthreads();
            #pragma unroll
            for (int r = 0; r < 16; ++r)
                buf2[swz(256 * r + t)] = make_uint2(h2u(x0[r]), h2u(x1[r]));
            __syncthreads();
            #pragma unroll
            for (int r = 0; r < 16; ++r) {
                const uint2 u = buf2[swz(256 * t1 + 16 * r + t0)];
                x0[r] = u2h(u.x); x1[r] = u2h(u.y);
            }
            h16h(x0); h16h(x1);               // round B (stride 16)
            __syncthreads();
            #pragma unroll
            for (int r = 0; r < 16; ++r)
                buf2[swz(256 * t1 + 16 * r + t0)] = make_uint2(h2u(x0[r]), h2u(x1[r]));
            __syncthreads();
            #pragma unroll
            for (int r = 0; r < 16; ++r) {
                const uint2 u = buf2[swz(256 * t1 + 16 * t0 + r)];
                x0[r] = u2h(u.x); x1[r] = u2h(u.y);
            }
            h16h(x0); h16h(x1);               // round C (stride 1)
            if (pass == 0) {                  // permutation + G (gather -> A-layout)
                __syncthreads();
                #pragma unroll
                for (int r = 0; r < 16; ++r)
                    buf2[swz(256 * t1 + 16 * t0 + r)] = make_uint2(h2u(x0[r]), h2u(x1[r]));
                __syncthreads();
                #pragma unroll
                for (int r = 0; r < 16; ++r) {
                    const uint2 u = buf2[PAv[r]];
                    x0[r] = Gh[r] * u2h(u.x);  // -> v_pk_mul_f16
                    x1[r] = Gh[r] * u2h(u.y);
                }
            }
        }

        // ---- redistribute outputs: j = 16t + r lives in t<32; give thread t oc=2t,2t+1
        __syncthreads();
        float* bufF = reinterpret_cast<float*>(buf2);  // fp32 staging (2048 floats)
        if (t < 32) {
            #pragma unroll
            for (int r = 0; r < 16; ++r) {
                const int a = 16 * t + (r ^ (t & 15));  // 2-way max bank aliasing
                bufF[a       ] = (float)x0[r].x;   // ow = p
                bufF[a +  512] = (float)x1[r].x;   // ow = p+8
                bufF[a + 1024] = (float)x0[r].y;   // ow = p+16
                bufF[a + 1536] = (float)x1[r].y;   // ow = p+24
            }
        }
        __syncthreads();
        const int a0 = (2 * t) ^ ((t >> 3) & 15), a1 = a0 ^ 1;
        #pragma unroll
        for (int k = 0; k < 4; ++k) {
            const float oA = S0 * bufF[a0 + 512 * k] + C0;   // oc=2t,   ow=p+8k
            const float oB = S1 * bufF[a1 + 512 * k] + C1;   // oc=2t+1, ow=p+8k
            if (!direct) {
                const int pix = ((b * 32 + oh) * 32 + p + 8 * k);
                *reinterpret_cast<float2*>(ws + (size_t)pix * 512 + 2 * t)
                    = make_float2(oA, oB);
            } else {
                const size_t r0 = ((size_t)b * 512 + 2 * t) * 1024 + oh * 32 + p + 8 * k;
                out[r0]        = oA;
                out[r0 + 1024] = oB;
            }
        }
    }
}

// ws (b,oh,ow,oc) -> out (b,oc,oh,ow).
// R3: LDS-staged transpose. Block = (b,oh). 16 chunks of [32 ow][32 oc], 8 chunks per
// LDS fill ([8][32][33] padded floats, 33.8 KiB). Read phase: float4 along oc, lanes
// contiguous -> 128B coalesced segments. Write phase: float4 along ow -> each oc row's
// full 128B line written by 8 lanes. Both LDS phases <=2-way bank aliasing.
__global__ __launch_bounds__(256)
void transpose_kernel(const float* __restrict__ ws, float* __restrict__ out)
{
    __shared__ float tile[8][32][33];

    const int t  = threadIdx.x;
    const int b  = blockIdx.x >> 5;
    const int oh = blockIdx.x & 31;
    const float* src = ws + (size_t)((b * 32 + oh) * 32) * 512;  // [ow][oc]

    const int ow_r = t >> 3;   // 0..31  read phase: ow row
    const int oq   = t & 7;    // 0..7   read phase: float4 group within 32 oc
    const int oc_w = t >> 3;   // 0..31  write phase: oc within chunk
    const int wq   = t & 7;    // 0..7   write phase: float4 group within 32 ow

    #pragma unroll
    for (int outer = 0; outer < 2; ++outer) {
        #pragma unroll
        for (int cc = 0; cc < 8; ++cc) {
            const int oc0 = (outer * 8 + cc) * 32;
            const float4 v = *reinterpret_cast<const float4*>(
                src + (size_t)ow_r * 512 + oc0 + 4 * oq);
            tile[cc][ow_r][4 * oq + 0] = v.x;
            tile[cc][ow_r][4 * oq + 1] = v.y;
            tile[cc][ow_r][4 * oq + 2] = v.z;
            tile[cc][ow_r][4 * oq + 3] = v.w;
        }
        __syncthreads();
        #pragma unroll
        for (int cc = 0; cc < 8; ++cc) {
            const int oc = (outer * 8 + cc) * 32 + oc_w;
            float4 v;
            v.x = tile[cc][4 * wq + 0][oc_w];
            v.y = tile[cc][4 * wq + 1][oc_w];
            v.z = tile[cc][4 * wq + 2][oc_w];
            v.w = tile[cc][4 * wq + 3][oc_w];
            *reinterpret_cast<float4*>(
                out + ((size_t)b * 512 + oc) * 1024 + oh * 32 + 4 * wq) = v;
        }
        __syncthreads();
    }
}

extern "C" void kernel_launch(void* const* d_in, const int* in_sizes, int n_in,
                              void* d_out, int out_size, void* d_ws, size_t ws_size,
                              hipStream_t stream) {
    const float* in   = (const float*)d_in[0];
    const float* Bm   = (const float*)d_in[1];
    const float* Gm   = (const float*)d_in[2];
    const float* Sm   = (const float*)d_in[3];
    const float* bias = (const float*)d_in[4];
    const int*   P    = (const int*)d_in[5];
    float* out = (float*)d_out;
    float* ws  = (float*)d_ws;

    const size_t need = (size_t)16 * 32 * 32 * 512 * 4;  // 33.5 MB pixel-major staging
    const int direct = (ws_size < need) ? 1 : 0;

    dim3 grid(16 * 32), block(256);
    fastfood_kernel<<<grid, block, 0, stream>>>(in, Bm, Gm, Sm, bias, P, ws, out, direct);
    if (!direct)
        transpose_kernel<<<grid, block, 0, stream>>>(ws, out);
}

// Round 4
// 141.640 us; speedup vs baseline: 1.4057x; 1.0415x over previous
//
#include <hip/hip_runtime.h>
#include <hip/hip_bf16.h>
#include <stdint.h>

// Fastfood 2D conv, MI355X. fp32 I/O:
// input (16,256,32,32), B/G/S (1,4096), bias (512), P (4096) i32 -> out (16,512,32,32).
// Per pixel: patch j=kk*256+ch (2304, pad 4096), *B, FWHT4096, perm P, *G, FWHT4096,
// *S[0:512]+bias.
//
// R4: pixel QUADS (ow = p, p+8, p+16, p+24), 4 px packed per uint2 LDS slot (b64
// exchanges at swizzled conflict-free addresses).
// R5: fp16 native pipeline: values are packed _Float16x2 (h2); butterflies are
// v_pk_add_f16; LDS exchange is a pure bitcast (no pack/unpack VALU).
// R6: (a) WAR-barrier elimination 12->9 per quad: the post-round-B write and the
//     perm-staging write target each thread's OWN just-read slots (per-thread
//     disjoint partitions; swz is a bijection so disjointness is preserved) ->
//     no barrier needed between read and write-back. (b) ws stored as raw f16
//     (h2 per oc-pair, pixel-major): zero extra rounding (pipeline is already
//     f16); S*x+bias moves to the memory-bound transpose kernel in f32.
//     (c) epilogue stages raw h2 words: owner writes halve; readers repack with
//     v_pack_b32_f16.
// LDS: 48 KiB s_in + 32 KiB buf = 80 KiB -> 2 blocks/CU.

typedef _Float16 h2 __attribute__((ext_vector_type(2)));

__device__ __forceinline__ float bf2f(uint16_t u) {
    union { uint32_t i; float f; } c; c.i = ((uint32_t)u) << 16; return c.f;
}
__device__ __forceinline__ uint16_t f2bf(float f) {  // RNE
    uint32_t u = __float_as_uint(f);
    return (uint16_t)((u + 0x7FFFu + ((u >> 16) & 1u)) >> 16);
}
__device__ __forceinline__ int swz(int j) {
    return j ^ ((j >> 5) & 7) ^ (((j >> 8) & 1) * 24) ^ (((j >> 9) & 1) * 8);
}
__device__ __forceinline__ uint32_t h2u(h2 v) {
    union { h2 h; uint32_t u; } c; c.h = v; return c.u;
}
__device__ __forceinline__ h2 u2h(uint32_t x) {
    union { h2 h; uint32_t u; } c; c.u = x; return c.h;
}
__device__ __forceinline__ h2 pkh(float a, float b) {
    h2 r; r.x = (_Float16)a; r.y = (_Float16)b; return r;
}
__device__ __forceinline__ uint32_t packh(_Float16 a, _Float16 b) {  // v_pack_b32_f16
    h2 r; r.x = a; r.y = b; return h2u(r);
}
__device__ __forceinline__ void h16h(h2* x) {
    #pragma unroll
    for (int h = 1; h < 16; h <<= 1) {
        #pragma unroll
        for (int g = 0; g < 16; g += 2 * h) {
            #pragma unroll
            for (int u = g; u < g + h; ++u) {
                h2 a = x[u], b = x[u + h];
                x[u]     = a + b;   // -> v_pk_add_f16
                x[u + h] = a - b;
            }
        }
    }
}

__global__ __launch_bounds__(256, 2)
void fastfood_kernel(const float* __restrict__ in,
                     const float* __restrict__ Bm,
                     const float* __restrict__ Gm,
                     const float* __restrict__ Sm,
                     const float* __restrict__ bias,
                     const int* __restrict__ P,
                     float* __restrict__ ws,    // uint (h2) staging when !direct
                     float* __restrict__ out,   // used only when direct!=0
                     int direct)
{
    __shared__ uint16_t s_in[3 * 32 * 256];   // [ihrel][iw][ch] bf16, 48 KiB
    __shared__ uint2    buf2[4096];           // swizzled 4-pixel fp16 exchange, 32 KiB

    const int t  = threadIdx.x;
    const int t1 = t >> 4, t0 = t & 15;
    const int b  = blockIdx.x >> 5;
    const int oh = blockIdx.x & 31;

    // ---- stage input rows oh-1..oh+1 into LDS (coalesced float4)
    #pragma unroll
    for (int i = 0; i < 24; ++i) {
        const int idx   = t + i * 256;
        const int part  = idx & 7;
        const int ch    = (idx >> 3) & 255;
        const int ihrel = idx >> 11;
        const int ih    = oh - 1 + ihrel;
        float4 ld = make_float4(0.f, 0.f, 0.f, 0.f);
        if ((unsigned)ih < 32u) {
            ld = *reinterpret_cast<const float4*>(
                in + ((((size_t)b * 256 + ch) * 32 + ih) * 32 + part * 4));
        }
        const int base = ((ihrel * 32 + part * 4) << 8) | ch;
        s_in[base      ] = f2bf(ld.x);
        s_in[base + 256] = f2bf(ld.y);
        s_in[base + 512] = f2bf(ld.z);
        s_in[base + 768] = f2bf(ld.w);
    }

    // ---- constants
    float Bv[9];
    #pragma unroll
    for (int r = 0; r < 9; ++r) Bv[r] = Bm[r * 256 + t];
    h2 Gh[16]; int PAv[16];
    #pragma unroll
    for (int r = 0; r < 16; ++r) {
        const float g = Gm[r * 256 + t];
        Gh[r]  = pkh(g, g);
        PAv[r] = swz(P[r * 256 + t]);
    }
    const float S0 = Sm[2 * t], S1 = Sm[2 * t + 1];
    const float C0 = bias[2 * t], C1 = bias[2 * t + 1];
    __syncthreads();

    for (int p = 0; p < 8; ++p) {             // pixel quad (ow = p, p+8, p+16, p+24)
        h2 x0[16], x1[16];                    // x0=(p, p+16), x1=(p+8, p+24)
        #pragma unroll
        for (int r = 0; r < 9; ++r) {
            const int kh = r / 3, kw = r % 3;
            const int iw = p - 1 + kw;        // iw in [-1, 9]
            float v0 = 0.f, v3 = 0.f;
            if ((unsigned)iw < 32u)        v0 = bf2f(s_in[((kh * 32 + iw     ) << 8) | t]);
            const float v1                    = bf2f(s_in[((kh * 32 + iw +  8) << 8) | t]);
            const float v2                    = bf2f(s_in[((kh * 32 + iw + 16) << 8) | t]);
            if ((unsigned)(iw + 24) < 32u) v3 = bf2f(s_in[((kh * 32 + iw + 24) << 8) | t]);
            x0[r] = pkh(v0 * Bv[r], v2 * Bv[r]);
            x1[r] = pkh(v1 * Bv[r], v3 * Bv[r]);
        }
        #pragma unroll
        for (int r = 9; r < 16; ++r) {
            x0[r] = pkh(0.f, 0.f);
            x1[r] = pkh(0.f, 0.f);
        }

        #pragma unroll
        for (int pass = 0; pass < 2; ++pass) {
            h16h(x0); h16h(x1);               // round A (stride 256)
            __syncthreads();                  // WAR: prior reads of buf anywhere
            #pragma unroll
            for (int r = 0; r < 16; ++r)
                buf2[swz(256 * r + t)] = make_uint2(h2u(x0[r]), h2u(x1[r]));
            __syncthreads();                  // RAW
            #pragma unroll
            for (int r = 0; r < 16; ++r) {
                const uint2 u = buf2[swz(256 * t1 + 16 * r + t0)];
                x0[r] = u2h(u.x); x1[r] = u2h(u.y);
            }
            h16h(x0); h16h(x1);               // round B (stride 16)
            // NO barrier: write-back to this thread's own just-read slots
            // (per-thread disjoint address partition; swz bijective).
            #pragma unroll
            for (int r = 0; r < 16; ++r)
                buf2[swz(256 * t1 + 16 * r + t0)] = make_uint2(h2u(x0[r]), h2u(x1[r]));
            __syncthreads();                  // RAW
            #pragma unroll
            for (int r = 0; r < 16; ++r) {
                const uint2 u = buf2[swz(256 * t1 + 16 * t0 + r)];
                x0[r] = u2h(u.x); x1[r] = u2h(u.y);
            }
            h16h(x0); h16h(x1);               // round C (stride 1)
            if (pass == 0) {                  // permutation + G (gather -> A-layout)
                // NO barrier: same slots as just-read (own partition).
                #pragma unroll
                for (int r = 0; r < 16; ++r)
                    buf2[swz(256 * t1 + 16 * t0 + r)] = make_uint2(h2u(x0[r]), h2u(x1[r]));
                __syncthreads();              // RAW before arbitrary-address gather
                #pragma unroll
                for (int r = 0; r < 16; ++r) {
                    const uint2 u = buf2[PAv[r]];
                    x0[r] = Gh[r] * u2h(u.x);  // -> v_pk_mul_f16
                    x1[r] = Gh[r] * u2h(u.y);
                }
            }
        }

        // ---- redistribute: oc j=16t+r lives in t<32 (C-layout); give thread t
        //      the h2 words for oc=2t,2t+1. Raw h2 staging (no unpack/convert).
        __syncthreads();                      // WAR vs round-C reads
        uint32_t* bu = reinterpret_cast<uint32_t*>(buf2);
        if (t < 32) {
            #pragma unroll
            for (int r = 0; r < 16; ++r) {
                const int a = 16 * t + (r ^ (t & 15));  // 2-way max bank aliasing
                bu[a]       = h2u(x0[r]);   // (ow p, p+16) of oc=16t+r
                bu[a + 512] = h2u(x1[r]);   // (ow p+8, p+24)
            }
        }
        __syncthreads();                      // RAW
        const int a0 = (2 * t) ^ ((t >> 3) & 15), a1 = a0 ^ 1;
        const h2 A0 = u2h(bu[a0]),       B0 = u2h(bu[a1]);        // oc0/oc1 @ (p, p+16)
        const h2 A1 = u2h(bu[a0 + 512]), B1 = u2h(bu[a1 + 512]);  // oc0/oc1 @ (p+8, p+24)

        if (!direct) {
            uint32_t* wsu = reinterpret_cast<uint32_t*>(ws);
            const int pix0 = ((b * 32 + oh) * 32 + p);
            wsu[(size_t)(pix0     ) * 256 + t] = packh(A0.x, B0.x);  // ow p
            wsu[(size_t)(pix0 +  8) * 256 + t] = packh(A1.x, B1.x);  // ow p+8
            wsu[(size_t)(pix0 + 16) * 256 + t] = packh(A0.y, B0.y);  // ow p+16
            wsu[(size_t)(pix0 + 24) * 256 + t] = packh(A1.y, B1.y);  // ow p+24
        } else {
            const size_t r0 = ((size_t)b * 512 + 2 * t) * 1024 + oh * 32;
            out[r0 + p]             = S0 * (float)A0.x + C0;
            out[r0 + 1024 + p]      = S1 * (float)B0.x + C1;
            out[r0 + p + 8]         = S0 * (float)A1.x + C0;
            out[r0 + 1024 + p + 8]  = S1 * (float)B1.x + C1;
            out[r0 + p + 16]        = S0 * (float)A0.y + C0;
            out[r0 + 1024 + p + 16] = S1 * (float)B0.y + C1;
            out[r0 + p + 24]        = S0 * (float)A1.y + C0;
            out[r0 + 1024 + p + 24] = S1 * (float)B1.y + C1;
        }
    }
}

// ws (b,oh,ow,cpair) h2 -> out (b,oc,oh,ow) f32, applying S*x+bias in f32.
// R6: single LDS fill [8][32][33] uint (33 KiB), ONE barrier per block.
// Read: uint4 along cpair (8 full lines/wave). Write: per cpair, unpack h2 ->
// two f32 rows, 2x float4 stores (8 full 128B lines/wave-instr). <=2-way banks.
__global__ __launch_bounds__(256)
void transpose_kernel(const float* __restrict__ wsf,
                      const float* __restrict__ Sm,
                      const float* __restrict__ bias,
                      float* __restrict__ out)
{
    __shared__ uint32_t tile[8][32][33];

    const int t  = threadIdx.x;
    const int b  = blockIdx.x >> 5;
    const int oh = blockIdx.x & 31;
    const uint32_t* src = reinterpret_cast<const uint32_t*>(wsf)
                        + (size_t)((b * 32 + oh) * 32) * 256;  // [ow][cpair]

    const int ow_r = t >> 3, oq = t & 7;   // read phase
    const int c_w  = t >> 3, wq = t & 7;   // write phase

    #pragma unroll
    for (int cc = 0; cc < 8; ++cc) {
        const uint4 v = *reinterpret_cast<const uint4*>(
            src + (size_t)ow_r * 256 + cc * 32 + 4 * oq);
        tile[cc][ow_r][4 * oq + 0] = v.x;
        tile[cc][ow_r][4 * oq + 1] = v.y;
        tile[cc][ow_r][4 * oq + 2] = v.z;
        tile[cc][ow_r][4 * oq + 3] = v.w;
    }
    __syncthreads();
    #pragma unroll
    for (int cc = 0; cc < 8; ++cc) {
        const int cp  = cc * 32 + c_w;         // global oc-pair
        const int oc0 = 2 * cp;
        const float2 Sv = *reinterpret_cast<const float2*>(Sm + oc0);
        const float2 Cv = *reinterpret_cast<const float2*>(bias + oc0);
        float4 r0, r1;
        {
            h2 h;
            h = u2h(tile[cc][4 * wq + 0][c_w]);
            r0.x = Sv.x * (float)h.x + Cv.x;  r1.x = Sv.y * (float)h.y + Cv.y;
            h = u2h(tile[cc][4 * wq + 1][c_w]);
            r0.y = Sv.x * (float)h.x + Cv.x;  r1.y = Sv.y * (float)h.y + Cv.y;
            h = u2h(tile[cc][4 * wq + 2][c_w]);
            r0.z = Sv.x * (float)h.x + Cv.x;  r1.z = Sv.y * (float)h.y + Cv.y;
            h = u2h(tile[cc][4 * wq + 3][c_w]);
            r0.w = Sv.x * (float)h.x + Cv.x;  r1.w = Sv.y * (float)h.y + Cv.y;
        }
        float* dst = out + ((size_t)b * 512 + oc0) * 1024 + oh * 32 + 4 * wq;
        *reinterpret_cast<float4*>(dst)        = r0;   // oc0 row
        *reinterpret_cast<float4*>(dst + 1024) = r1;   // oc0+1 row
    }
}

extern "C" void kernel_launch(void* const* d_in, const int* in_sizes, int n_in,
                              void* d_out, int out_size, void* d_ws, size_t ws_size,
                              hipStream_t stream) {
    const float* in   = (const float*)d_in[0];
    const float* Bm   = (const float*)d_in[1];
    const float* Gm   = (const float*)d_in[2];
    const float* Sm   = (const float*)d_in[3];
    const float* bias = (const float*)d_in[4];
    const int*   P    = (const int*)d_in[5];
    float* out = (float*)d_out;
    float* ws  = (float*)d_ws;

    const size_t need = (size_t)16 * 32 * 32 * 512 * 2;  // 16.8 MB h2 pixel-major staging
    const int direct = (ws_size < need) ? 1 : 0;

    dim3 grid(16 * 32), block(256);
    fastfood_kernel<<<grid, block, 0, stream>>>(in, Bm, Gm, Sm, bias, P, ws, out, direct);
    if (!direct)
        transpose_kernel<<<grid, block, 0, stream>>>(ws, Sm, bias, out);
}